// Round 1
// baseline (607.252 us; speedup 1.0000x reference)
//
#include <hip/hip_runtime.h>
#include <hip/hip_bf16.h>

// Problem constants
#define B_ 16
#define T_ 1024
#define D_ 1024

// GEMM tile constants
#define BM 128
#define BN 128
#define BK 32
#define LDS_STRIDE 40  // 32 + 8 pad (bf16 elems); keeps 16B alignment for b128 frag reads

using frag8 = __attribute__((ext_vector_type(8))) short;   // 8 bf16 (4 VGPRs)
using f32x4 = __attribute__((ext_vector_type(4))) float;   // 4 fp32 acc

__device__ inline unsigned short f2bf(float f) {
    union { float f; unsigned u; } v; v.f = f;
    unsigned r = v.u + 0x7FFF + ((v.u >> 16) & 1);   // round-nearest-even
    return (unsigned short)(r >> 16);
}

// ---------------------------------------------------------------------------
// K1: fused Q/K/V projection.  q = x @ W + b, cast to bf16.
// x: [B*T, D] fp32 row-major.  W: [D, D] fp32 (k-major rows, n contiguous).
// grid: (N/BN=8, M/BM=128, 3)   block: 256
// ---------------------------------------------------------------------------
__global__ __launch_bounds__(256)
void qkv_gemm(const float* __restrict__ x,
              const float* __restrict__ Wq, const float* __restrict__ bq,
              const float* __restrict__ Wk, const float* __restrict__ bk,
              const float* __restrict__ Wv, const float* __restrict__ bv,
              unsigned short* __restrict__ qb,
              unsigned short* __restrict__ kb,
              unsigned short* __restrict__ vb) {
    __shared__ __align__(16) unsigned short As[BM * LDS_STRIDE];
    __shared__ __align__(16) unsigned short Bs[BN * LDS_STRIDE];

    const float* W; const float* bias; unsigned short* out;
    if (blockIdx.z == 0)      { W = Wq; bias = bq; out = qb; }
    else if (blockIdx.z == 1) { W = Wk; bias = bk; out = kb; }
    else                      { W = Wv; bias = bv; out = vb; }

    const int n0   = blockIdx.x * BN;
    const int m0   = blockIdx.y * BM;
    const int tid  = threadIdx.x;
    const int lane = tid & 63;
    const int wave = tid >> 6;
    const int wm   = (wave >> 1) * 64;
    const int wn   = (wave & 1) * 64;

    f32x4 acc[4][4];
#pragma unroll
    for (int i = 0; i < 4; i++)
#pragma unroll
        for (int j = 0; j < 4; j++) acc[i][j] = (f32x4){0.f, 0.f, 0.f, 0.f};

    const int ak  = tid & 31;   // A: k index
    const int am  = tid >> 5;   // A: m row base (0..7)
    const int bn  = tid & 127;  // B: n index (coalesced)
    const int bk0 = tid >> 7;   // B: k row base (0..1)

    const int fr = lane & 15;
    const int fk = (lane >> 4) * 8;

    for (int k0 = 0; k0 < D_; k0 += BK) {
        // A tile: As[m][k] = bf16(x[(m0+m)*D + k0+k])   (coalesced fp32 along k)
#pragma unroll
        for (int it = 0; it < 16; ++it) {
            int m = am + it * 8;
            As[m * LDS_STRIDE + ak] = f2bf(x[(size_t)(m0 + m) * D_ + k0 + ak]);
        }
        // B tile (transposed into LDS): Bs[n][k] = bf16(W[(k0+k)*D + n0+n])
#pragma unroll
        for (int it = 0; it < 16; ++it) {
            int kk = bk0 + it * 2;
            Bs[bn * LDS_STRIDE + kk] = f2bf(W[(size_t)(k0 + kk) * D_ + n0 + bn]);
        }
        __syncthreads();

        frag8 af[4], bf[4];
#pragma unroll
        for (int t = 0; t < 4; ++t)
            af[t] = *(const frag8*)&As[(wm + t * 16 + fr) * LDS_STRIDE + fk];
#pragma unroll
        for (int t = 0; t < 4; ++t)
            bf[t] = *(const frag8*)&Bs[(wn + t * 16 + fr) * LDS_STRIDE + fk];
#pragma unroll
        for (int i = 0; i < 4; i++)
#pragma unroll
            for (int j = 0; j < 4; j++)
                acc[i][j] = __builtin_amdgcn_mfma_f32_16x16x32_bf16(
                    af[i], bf[j], acc[i][j], 0, 0, 0);
        __syncthreads();
    }

    // epilogue: +bias, cast bf16, store
    const int col   = lane & 15;
    const int rbase = (lane >> 4) * 4;
#pragma unroll
    for (int i = 0; i < 4; i++) {
#pragma unroll
        for (int j = 0; j < 4; j++) {
            int gn = n0 + wn + j * 16 + col;
            float bb = bias[gn];
#pragma unroll
            for (int r = 0; r < 4; r++) {
                int gm = m0 + wm + i * 16 + rbase + r;
                out[(size_t)gm * D_ + gn] = f2bf(acc[i][j][r] + bb);
            }
        }
    }
}

// ---------------------------------------------------------------------------
// K2: scores TRANSPOSED.  ST[b][i=key][j=query] = scale * (k_i . q_j)
// Both operands row-major [T, D] bf16, contraction along contiguous D.
// grid: (T/BN=8, T/BM=8, B=16)
// ---------------------------------------------------------------------------
__global__ __launch_bounds__(256)
void score_gemm(const unsigned short* __restrict__ kbuf,
                const unsigned short* __restrict__ qbuf,
                float* __restrict__ st) {
    __shared__ __align__(16) unsigned short As[BM * LDS_STRIDE];
    __shared__ __align__(16) unsigned short Bs[BN * LDS_STRIDE];

    const int b  = blockIdx.z;
    const int j0 = blockIdx.x * BN;   // query block
    const int i0 = blockIdx.y * BM;   // key block
    const unsigned short* A  = kbuf + (size_t)b * T_ * D_;
    const unsigned short* Bq = qbuf + (size_t)b * T_ * D_;

    const int tid  = threadIdx.x;
    const int lane = tid & 63;
    const int wave = tid >> 6;
    const int wm   = (wave >> 1) * 64;
    const int wn   = (wave & 1) * 64;

    f32x4 acc[4][4];
#pragma unroll
    for (int i = 0; i < 4; i++)
#pragma unroll
        for (int j = 0; j < 4; j++) acc[i][j] = (f32x4){0.f, 0.f, 0.f, 0.f};

    const int ak = tid & 31;
    const int am = tid >> 5;
    const int fr = lane & 15;
    const int fk = (lane >> 4) * 8;

    for (int k0 = 0; k0 < D_; k0 += BK) {
#pragma unroll
        for (int it = 0; it < 16; ++it) {
            int m = am + it * 8;
            As[m * LDS_STRIDE + ak] = A[(size_t)(i0 + m) * D_ + k0 + ak];
            Bs[m * LDS_STRIDE + ak] = Bq[(size_t)(j0 + m) * D_ + k0 + ak];
        }
        __syncthreads();

        frag8 af[4], bf[4];
#pragma unroll
        for (int t = 0; t < 4; ++t)
            af[t] = *(const frag8*)&As[(wm + t * 16 + fr) * LDS_STRIDE + fk];
#pragma unroll
        for (int t = 0; t < 4; ++t)
            bf[t] = *(const frag8*)&Bs[(wn + t * 16 + fr) * LDS_STRIDE + fk];
#pragma unroll
        for (int i = 0; i < 4; i++)
#pragma unroll
            for (int j = 0; j < 4; j++)
                acc[i][j] = __builtin_amdgcn_mfma_f32_16x16x32_bf16(
                    af[i], bf[j], acc[i][j], 0, 0, 0);
        __syncthreads();
    }

    const float scale = 0.03125f;  // 1/sqrt(1024)
    const int col   = lane & 15;
    const int rbase = (lane >> 4) * 4;
    float* outb = st + (size_t)b * T_ * T_;
#pragma unroll
    for (int i = 0; i < 4; i++) {
#pragma unroll
        for (int j = 0; j < 4; j++) {
            int gj = j0 + wn + j * 16 + col;
#pragma unroll
            for (int r = 0; r < 4; r++) {
                int gi = i0 + wm + i * 16 + rbase + r;
                outb[(size_t)gi * T_ + gj] = acc[i][j][r] * scale;
            }
        }
    }
}

// ---------------------------------------------------------------------------
// K3: row softmax over ST rows (= softmax over the QUERY axis of attn),
// write bf16 P^T.  grid: B*T = 16384 blocks, 256 threads.
// ---------------------------------------------------------------------------
__global__ __launch_bounds__(256)
void softmax_rows(const float* __restrict__ st, unsigned short* __restrict__ pt) {
    const size_t row = blockIdx.x;
    const float* r = st + row * T_;
    unsigned short* o = pt + row * T_;
    const int tid  = threadIdx.x;
    const int lane = tid & 63;
    const int wave = tid >> 6;

    float v0 = r[tid], v1 = r[tid + 256], v2 = r[tid + 512], v3 = r[tid + 768];
    float mx = fmaxf(fmaxf(v0, v1), fmaxf(v2, v3));
#pragma unroll
    for (int off = 32; off; off >>= 1) mx = fmaxf(mx, __shfl_down(mx, off));
    __shared__ float sm[4];
    if (lane == 0) sm[wave] = mx;
    __syncthreads();
    mx = fmaxf(fmaxf(sm[0], sm[1]), fmaxf(sm[2], sm[3]));

    float e0 = __expf(v0 - mx), e1 = __expf(v1 - mx);
    float e2 = __expf(v2 - mx), e3 = __expf(v3 - mx);
    float s = e0 + e1 + e2 + e3;
#pragma unroll
    for (int off = 32; off; off >>= 1) s += __shfl_down(s, off);
    __shared__ float ss[4];
    if (lane == 0) ss[wave] = s;
    __syncthreads();
    s = ss[0] + ss[1] + ss[2] + ss[3];
    float inv = 1.f / s;

    o[tid]       = f2bf(e0 * inv);
    o[tid + 256] = f2bf(e1 * inv);
    o[tid + 512] = f2bf(e2 * inv);
    o[tid + 768] = f2bf(e3 * inv);
}

// ---------------------------------------------------------------------------
// K4: out = P^T-contracted with V, fused with the rank-1 FC:
//   res[b] += sum_{q,d} (sum_i P^T[b][i][q] * V[b][i][d]) * Wfc[q*D+d]
// Both operands K-major (contraction i along global rows) -> transposed LDS staging.
// grid: (D/BN=8, T/BM=8, B=16)
// ---------------------------------------------------------------------------
__global__ __launch_bounds__(256)
void pv_fc(const unsigned short* __restrict__ pt,
           const unsigned short* __restrict__ vbuf,
           const float* __restrict__ Wfc,
           float* __restrict__ outv) {
    __shared__ __align__(16) unsigned short As[BM * LDS_STRIDE];
    __shared__ __align__(16) unsigned short Bs[BN * LDS_STRIDE];

    const int b  = blockIdx.z;
    const int d0 = blockIdx.x * BN;
    const int q0 = blockIdx.y * BM;
    const unsigned short* P = pt   + (size_t)b * T_ * T_;  // [i][q]
    const unsigned short* V = vbuf + (size_t)b * T_ * D_;  // [i][d]

    const int tid  = threadIdx.x;
    const int lane = tid & 63;
    const int wave = tid >> 6;
    const int wm   = (wave >> 1) * 64;
    const int wn   = (wave & 1) * 64;

    f32x4 acc[4][4];
#pragma unroll
    for (int i = 0; i < 4; i++)
#pragma unroll
        for (int j = 0; j < 4; j++) acc[i][j] = (f32x4){0.f, 0.f, 0.f, 0.f};

    const int cidx = tid & 127;   // q or d (coalesced global dim)
    const int rk   = tid >> 7;    // i row base (0..1)
    const int fr = lane & 15;
    const int fk = (lane >> 4) * 8;

    for (int k0 = 0; k0 < T_; k0 += BK) {
        // transposed staging: As[q][i], Bs[d][i]
#pragma unroll
        for (int it = 0; it < 16; ++it) {
            int ii = rk + it * 2;
            As[cidx * LDS_STRIDE + ii] = P[(size_t)(k0 + ii) * T_ + q0 + cidx];
            Bs[cidx * LDS_STRIDE + ii] = V[(size_t)(k0 + ii) * D_ + d0 + cidx];
        }
        __syncthreads();

        frag8 af[4], bf[4];
#pragma unroll
        for (int t = 0; t < 4; ++t)
            af[t] = *(const frag8*)&As[(wm + t * 16 + fr) * LDS_STRIDE + fk];
#pragma unroll
        for (int t = 0; t < 4; ++t)
            bf[t] = *(const frag8*)&Bs[(wn + t * 16 + fr) * LDS_STRIDE + fk];
#pragma unroll
        for (int i = 0; i < 4; i++)
#pragma unroll
            for (int j = 0; j < 4; j++)
                acc[i][j] = __builtin_amdgcn_mfma_f32_16x16x32_bf16(
                    af[i], bf[j], acc[i][j], 0, 0, 0);
        __syncthreads();
    }

    // fused FC epilogue: local dot with Wfc, then block-reduce + atomicAdd
    const int col   = lane & 15;
    const int rbase = (lane >> 4) * 4;
    float local = 0.f;
#pragma unroll
    for (int i = 0; i < 4; i++) {
#pragma unroll
        for (int j = 0; j < 4; j++) {
            int gd = d0 + wn + j * 16 + col;
#pragma unroll
            for (int r = 0; r < 4; r++) {
                int gq = q0 + wm + i * 16 + rbase + r;
                local += acc[i][j][r] * Wfc[(size_t)gq * D_ + gd];
            }
        }
    }
#pragma unroll
    for (int off = 32; off; off >>= 1) local += __shfl_down(local, off);
    __shared__ float wsum[4];
    if (lane == 0) wsum[wave] = local;
    __syncthreads();
    if (tid == 0) {
        float t = wsum[0] + wsum[1] + wsum[2] + wsum[3];
        atomicAdd(&outv[b], t);
    }
}

// K0: init output with bias (d_out is re-poisoned before every timed launch)
__global__ void init_out(float* __restrict__ out, const float* __restrict__ bfc) {
    if (threadIdx.x < B_) out[threadIdx.x] = bfc[0];
}

extern "C" void kernel_launch(void* const* d_in, const int* in_sizes, int n_in,
                              void* d_out, int out_size, void* d_ws, size_t ws_size,
                              hipStream_t stream) {
    const float* x   = (const float*)d_in[0];
    const float* Wq  = (const float*)d_in[1];
    const float* bq  = (const float*)d_in[2];
    const float* Wk  = (const float*)d_in[3];
    const float* bk  = (const float*)d_in[4];
    const float* Wv  = (const float*)d_in[5];
    const float* bv  = (const float*)d_in[6];
    const float* Wfc = (const float*)d_in[7];
    const float* bfc = (const float*)d_in[8];
    float* out = (float*)d_out;

    // workspace layout (192 MB total)
    char* ws = (char*)d_ws;
    unsigned short* qb = (unsigned short*)ws;                 // 32 MB bf16 [B*T, D]
    unsigned short* kb = qb + (size_t)B_ * T_ * D_;           // 32 MB
    unsigned short* vb = kb + (size_t)B_ * T_ * D_;           // 32 MB
    float*          st = (float*)(vb + (size_t)B_ * T_ * D_); // 64 MB fp32 [B, T, T] (transposed scores)
    unsigned short* pt = (unsigned short*)(st + (size_t)B_ * T_ * T_); // 32 MB bf16

    qkv_gemm   <<<dim3(8, 128, 3),  256, 0, stream>>>(x, Wq, bq, Wk, bk, Wv, bv, qb, kb, vb);
    score_gemm <<<dim3(8, 8, 16),   256, 0, stream>>>(kb, qb, st);
    softmax_rows<<<dim3(B_ * T_),   256, 0, stream>>>(st, pt);
    init_out   <<<1, 64, 0, stream>>>(out, bfc);
    pv_fc      <<<dim3(8, 8, 16),   256, 0, stream>>>(pt, vb, Wfc, out);
}

// Round 2
// 451.234 us; speedup vs baseline: 1.3458x; 1.3458x over previous
//
#include <hip/hip_runtime.h>
#include <hip/hip_bf16.h>

// Problem constants
#define B_ 16
#define T_ 1024
#define D_ 1024

// GEMM tile constants (padded-LDS kernels: score/pv)
#define BM 128
#define BN 128
#define BK 32
#define LDS_STRIDE 40  // 32 + 8 pad (bf16 elems); keeps 16B alignment for b128 frag reads

using frag8 = __attribute__((ext_vector_type(8))) short;   // 8 bf16 (4 VGPRs)
using f32x4 = __attribute__((ext_vector_type(4))) float;   // 4 fp32 acc

__device__ inline unsigned short f2bf(float f) {
    union { float f; unsigned u; } v; v.f = f;
    unsigned r = v.u + 0x7FFF + ((v.u >> 16) & 1);   // round-nearest-even
    return (unsigned short)(r >> 16);
}

// ---------------------------------------------------------------------------
// K0a: x fp32 -> bf16  (16M elems, float4 in / ushort4 out, pure BW)
// ---------------------------------------------------------------------------
__global__ __launch_bounds__(256)
void cvt_x(const float* __restrict__ x, unsigned short* __restrict__ xb) {
    int i = blockIdx.x * 256 + threadIdx.x;          // group of 4 elems
    float4 v = ((const float4*)x)[i];
    ushort4 o;
    o.x = f2bf(v.x); o.y = f2bf(v.y); o.z = f2bf(v.z); o.w = f2bf(v.w);
    ((ushort4*)xb)[i] = o;
}

// ---------------------------------------------------------------------------
// K0b: W fp32 [k][n] -> bf16 TRANSPOSED wt[z][n][k]  (64x64 LDS tile transpose)
// grid (16,16,3) block 256
// ---------------------------------------------------------------------------
__global__ __launch_bounds__(256)
void cvt_wt(const float* __restrict__ Wq, const float* __restrict__ Wk,
            const float* __restrict__ Wv, unsigned short* __restrict__ wt) {
    __shared__ unsigned short t[64][65];
    const float* W = (blockIdx.z == 0) ? Wq : (blockIdx.z == 1 ? Wk : Wv);
    const int n0 = blockIdx.x * 64, k0 = blockIdx.y * 64;
    const int tn = threadIdx.x & 63;   // coalesced over n
    const int tk = threadIdx.x >> 6;   // 0..3
#pragma unroll
    for (int it = 0; it < 16; ++it) {
        int k = tk + it * 4;
        t[tn][k] = f2bf(W[(size_t)(k0 + k) * D_ + n0 + tn]);
    }
    __syncthreads();
    const int wk = threadIdx.x & 63;   // coalesced over k
    const int wn = threadIdx.x >> 6;
#pragma unroll
    for (int it = 0; it < 16; ++it) {
        int n = wn + it * 4;
        wt[((size_t)blockIdx.z << 20) + (size_t)(n0 + n) * D_ + k0 + wk] = t[n][wk];
    }
}

// ---------------------------------------------------------------------------
// K1: fused Q/K/V projection, m97-style: bf16 inputs, both operands k-major,
// global_load_lds width=16 staging, unpadded 128x32 LDS tiles.
// XCD-aware swizzle: each XCD cohort (linear%8) owns 3 of the 24 (z,nblk)
// W-slabs so a 256 KB bf16 W-slab stays in its private L2; x streams via L3.
// grid: (8, 128, 3) linear = x + 8*y + 1024*z.   block: 256
// ---------------------------------------------------------------------------
__global__ __launch_bounds__(256)
void qkv_gemm2(const unsigned short* __restrict__ xb,
               const unsigned short* __restrict__ wt,
               const float* __restrict__ bq, const float* __restrict__ bk,
               const float* __restrict__ bv,
               unsigned short* __restrict__ qb,
               unsigned short* __restrict__ kb,
               unsigned short* __restrict__ vb) {
    __shared__ __align__(16) unsigned short As[128 * 32];
    __shared__ __align__(16) unsigned short Bs[128 * 32];

    const int l   = blockIdx.x + 8 * blockIdx.y + 1024 * blockIdx.z;
    const int xcd = l & 7;
    const int idx = l >> 3;                 // 0..383
    const int slab = xcd * 3 + (idx >> 7);  // 0..23
    const int mblk = idx & 127;
    const int z    = slab >> 3;
    const int nblk = slab & 7;

    const int m0 = mblk * 128, n0 = nblk * 128;
    const unsigned short* Wz = wt + ((size_t)z << 20);
    const float* bias  = (z == 0) ? bq : (z == 1 ? bk : bv);
    unsigned short* out = (z == 0) ? qb : (z == 1 ? kb : vb);

    const int tid = threadIdx.x, lane = tid & 63, wave = tid >> 6;
    const int wm = (wave >> 1) * 64, wn = (wave & 1) * 64;

    f32x4 acc[4][4];
#pragma unroll
    for (int i = 0; i < 4; i++)
#pragma unroll
        for (int j = 0; j < 4; j++) acc[i][j] = (f32x4){0.f, 0.f, 0.f, 0.f};

    // staging: each lane deposits 16B at ldsbase + lane*16; covers 16 rows x 32k
    const int srow = lane >> 2;          // row within 16-row group
    const int sk   = (lane & 3) * 8;     // k elem offset
    const int fr = lane & 15, fk = (lane >> 4) * 8;

    for (int k0 = 0; k0 < D_; k0 += 32) {
#pragma unroll
        for (int it = 0; it < 2; ++it) {
            const int rb = wave * 2 + it;           // 16-row group 0..7
            const int r  = rb * 16 + srow;
            __builtin_amdgcn_global_load_lds(
                (const __attribute__((address_space(1))) unsigned int*)
                    (xb + (size_t)(m0 + r) * D_ + k0 + sk),
                (__attribute__((address_space(3))) unsigned int*)(As + rb * 512),
                16, 0, 0);
            __builtin_amdgcn_global_load_lds(
                (const __attribute__((address_space(1))) unsigned int*)
                    (Wz + (size_t)(n0 + r) * D_ + k0 + sk),
                (__attribute__((address_space(3))) unsigned int*)(Bs + rb * 512),
                16, 0, 0);
        }
        __syncthreads();

        frag8 af[4], bff[4];
#pragma unroll
        for (int t = 0; t < 4; ++t)
            af[t] = *(const frag8*)&As[(wm + t * 16 + fr) * 32 + fk];
#pragma unroll
        for (int t = 0; t < 4; ++t)
            bff[t] = *(const frag8*)&Bs[(wn + t * 16 + fr) * 32 + fk];
#pragma unroll
        for (int i = 0; i < 4; i++)
#pragma unroll
            for (int j = 0; j < 4; j++)
                acc[i][j] = __builtin_amdgcn_mfma_f32_16x16x32_bf16(
                    af[i], bff[j], acc[i][j], 0, 0, 0);
        __syncthreads();
    }

    // epilogue: +bias, cast bf16, store
    const int col   = lane & 15;
    const int rbase = (lane >> 4) * 4;
#pragma unroll
    for (int i = 0; i < 4; i++) {
#pragma unroll
        for (int j = 0; j < 4; j++) {
            int gn = n0 + wn + j * 16 + col;
            float bb = bias[gn];
#pragma unroll
            for (int r = 0; r < 4; r++) {
                int gm = m0 + wm + i * 16 + rbase + r;
                out[(size_t)gm * D_ + gn] = f2bf(acc[i][j][r] + bb);
            }
        }
    }
}

// ---------------------------------------------------------------------------
// K2: scores TRANSPOSED.  ST[b][i=key][j=query] = scale * (k_i . q_j)
// Both operands row-major [T, D] bf16, contraction along contiguous D.
// grid: (T/BN=8, T/BM=8, B=16)
// ---------------------------------------------------------------------------
__global__ __launch_bounds__(256)
void score_gemm(const unsigned short* __restrict__ kbuf,
                const unsigned short* __restrict__ qbuf,
                float* __restrict__ st) {
    __shared__ __align__(16) unsigned short As[BM * LDS_STRIDE];
    __shared__ __align__(16) unsigned short Bs[BN * LDS_STRIDE];

    const int b  = blockIdx.z;
    const int j0 = blockIdx.x * BN;   // query block
    const int i0 = blockIdx.y * BM;   // key block
    const unsigned short* A  = kbuf + (size_t)b * T_ * D_;
    const unsigned short* Bq = qbuf + (size_t)b * T_ * D_;

    const int tid  = threadIdx.x;
    const int lane = tid & 63;
    const int wave = tid >> 6;
    const int wm   = (wave >> 1) * 64;
    const int wn   = (wave & 1) * 64;

    f32x4 acc[4][4];
#pragma unroll
    for (int i = 0; i < 4; i++)
#pragma unroll
        for (int j = 0; j < 4; j++) acc[i][j] = (f32x4){0.f, 0.f, 0.f, 0.f};

    const int ak = tid & 31;
    const int am = tid >> 5;
    const int fr = lane & 15;
    const int fk = (lane >> 4) * 8;

    for (int k0 = 0; k0 < D_; k0 += BK) {
#pragma unroll
        for (int it = 0; it < 16; ++it) {
            int m = am + it * 8;
            As[m * LDS_STRIDE + ak] = A[(size_t)(i0 + m) * D_ + k0 + ak];
            Bs[m * LDS_STRIDE + ak] = Bq[(size_t)(j0 + m) * D_ + k0 + ak];
        }
        __syncthreads();

        frag8 af[4], bf[4];
#pragma unroll
        for (int t = 0; t < 4; ++t)
            af[t] = *(const frag8*)&As[(wm + t * 16 + fr) * LDS_STRIDE + fk];
#pragma unroll
        for (int t = 0; t < 4; ++t)
            bf[t] = *(const frag8*)&Bs[(wn + t * 16 + fr) * LDS_STRIDE + fk];
#pragma unroll
        for (int i = 0; i < 4; i++)
#pragma unroll
            for (int j = 0; j < 4; j++)
                acc[i][j] = __builtin_amdgcn_mfma_f32_16x16x32_bf16(
                    af[i], bf[j], acc[i][j], 0, 0, 0);
        __syncthreads();
    }

    const float scale = 0.03125f;  // 1/sqrt(1024)
    const int col   = lane & 15;
    const int rbase = (lane >> 4) * 4;
    float* outb = st + (size_t)b * T_ * T_;
#pragma unroll
    for (int i = 0; i < 4; i++) {
#pragma unroll
        for (int j = 0; j < 4; j++) {
            int gj = j0 + wn + j * 16 + col;
#pragma unroll
            for (int r = 0; r < 4; r++) {
                int gi = i0 + wm + i * 16 + rbase + r;
                outb[(size_t)gi * T_ + gj] = acc[i][j][r] * scale;
            }
        }
    }
}

// ---------------------------------------------------------------------------
// K3: row softmax over ST rows (= softmax over the QUERY axis of attn),
// write bf16 P^T.  grid: B*T = 16384 blocks, 256 threads.
// ---------------------------------------------------------------------------
__global__ __launch_bounds__(256)
void softmax_rows(const float* __restrict__ st, unsigned short* __restrict__ pt) {
    const size_t row = blockIdx.x;
    const float* r = st + row * T_;
    unsigned short* o = pt + row * T_;
    const int tid  = threadIdx.x;
    const int lane = tid & 63;
    const int wave = tid >> 6;

    float v0 = r[tid], v1 = r[tid + 256], v2 = r[tid + 512], v3 = r[tid + 768];
    float mx = fmaxf(fmaxf(v0, v1), fmaxf(v2, v3));
#pragma unroll
    for (int off = 32; off; off >>= 1) mx = fmaxf(mx, __shfl_down(mx, off));
    __shared__ float sm[4];
    if (lane == 0) sm[wave] = mx;
    __syncthreads();
    mx = fmaxf(fmaxf(sm[0], sm[1]), fmaxf(sm[2], sm[3]));

    float e0 = __expf(v0 - mx), e1 = __expf(v1 - mx);
    float e2 = __expf(v2 - mx), e3 = __expf(v3 - mx);
    float s = e0 + e1 + e2 + e3;
#pragma unroll
    for (int off = 32; off; off >>= 1) s += __shfl_down(s, off);
    __shared__ float ss[4];
    if (lane == 0) ss[wave] = s;
    __syncthreads();
    s = ss[0] + ss[1] + ss[2] + ss[3];
    float inv = 1.f / s;

    o[tid]       = f2bf(e0 * inv);
    o[tid + 256] = f2bf(e1 * inv);
    o[tid + 512] = f2bf(e2 * inv);
    o[tid + 768] = f2bf(e3 * inv);
}

// ---------------------------------------------------------------------------
// K4: out = P^T-contracted with V, fused with the rank-1 FC:
//   res[b] += sum_{q,d} (sum_i P^T[b][i][q] * V[b][i][d]) * Wfc[q*D+d]
// Both operands K-major (contraction i along global rows) -> transposed LDS staging.
// grid: (D/BN=8, T/BM=8, B=16)
// ---------------------------------------------------------------------------
__global__ __launch_bounds__(256)
void pv_fc(const unsigned short* __restrict__ pt,
           const unsigned short* __restrict__ vbuf,
           const float* __restrict__ Wfc,
           float* __restrict__ outv) {
    __shared__ __align__(16) unsigned short As[BM * LDS_STRIDE];
    __shared__ __align__(16) unsigned short Bs[BN * LDS_STRIDE];

    const int b  = blockIdx.z;
    const int d0 = blockIdx.x * BN;
    const int q0 = blockIdx.y * BM;
    const unsigned short* P = pt   + (size_t)b * T_ * T_;  // [i][q]
    const unsigned short* V = vbuf + (size_t)b * T_ * D_;  // [i][d]

    const int tid  = threadIdx.x;
    const int lane = tid & 63;
    const int wave = tid >> 6;
    const int wm   = (wave >> 1) * 64;
    const int wn   = (wave & 1) * 64;

    f32x4 acc[4][4];
#pragma unroll
    for (int i = 0; i < 4; i++)
#pragma unroll
        for (int j = 0; j < 4; j++) acc[i][j] = (f32x4){0.f, 0.f, 0.f, 0.f};

    const int cidx = tid & 127;   // q or d (coalesced global dim)
    const int rk   = tid >> 7;    // i row base (0..1)
    const int fr = lane & 15;
    const int fk = (lane >> 4) * 8;

    for (int k0 = 0; k0 < T_; k0 += BK) {
        // transposed staging: As[q][i], Bs[d][i]
#pragma unroll
        for (int it = 0; it < 16; ++it) {
            int ii = rk + it * 2;
            As[cidx * LDS_STRIDE + ii] = P[(size_t)(k0 + ii) * T_ + q0 + cidx];
            Bs[cidx * LDS_STRIDE + ii] = V[(size_t)(k0 + ii) * D_ + d0 + cidx];
        }
        __syncthreads();

        frag8 af[4], bf[4];
#pragma unroll
        for (int t = 0; t < 4; ++t)
            af[t] = *(const frag8*)&As[(wm + t * 16 + fr) * LDS_STRIDE + fk];
#pragma unroll
        for (int t = 0; t < 4; ++t)
            bf[t] = *(const frag8*)&Bs[(wn + t * 16 + fr) * LDS_STRIDE + fk];
#pragma unroll
        for (int i = 0; i < 4; i++)
#pragma unroll
            for (int j = 0; j < 4; j++)
                acc[i][j] = __builtin_amdgcn_mfma_f32_16x16x32_bf16(
                    af[i], bf[j], acc[i][j], 0, 0, 0);
        __syncthreads();
    }

    // fused FC epilogue: local dot with Wfc, then block-reduce + atomicAdd
    const int col   = lane & 15;
    const int rbase = (lane >> 4) * 4;
    float local = 0.f;
#pragma unroll
    for (int i = 0; i < 4; i++) {
#pragma unroll
        for (int j = 0; j < 4; j++) {
            int gd = d0 + wn + j * 16 + col;
#pragma unroll
            for (int r = 0; r < 4; r++) {
                int gq = q0 + wm + i * 16 + rbase + r;
                local += acc[i][j][r] * Wfc[(size_t)gq * D_ + gd];
            }
        }
    }
#pragma unroll
    for (int off = 32; off; off >>= 1) local += __shfl_down(local, off);
    __shared__ float wsum[4];
    if (lane == 0) wsum[wave] = local;
    __syncthreads();
    if (tid == 0) {
        float t = wsum[0] + wsum[1] + wsum[2] + wsum[3];
        atomicAdd(&outv[b], t);
    }
}

// K0: init output with bias (d_out is re-poisoned before every timed launch)
__global__ void init_out(float* __restrict__ out, const float* __restrict__ bfc) {
    if (threadIdx.x < B_) out[threadIdx.x] = bfc[0];
}

extern "C" void kernel_launch(void* const* d_in, const int* in_sizes, int n_in,
                              void* d_out, int out_size, void* d_ws, size_t ws_size,
                              hipStream_t stream) {
    const float* x   = (const float*)d_in[0];
    const float* Wq  = (const float*)d_in[1];
    const float* bq  = (const float*)d_in[2];
    const float* Wk  = (const float*)d_in[3];
    const float* bk  = (const float*)d_in[4];
    const float* Wv  = (const float*)d_in[5];
    const float* bv  = (const float*)d_in[6];
    const float* Wfc = (const float*)d_in[7];
    const float* bfc = (const float*)d_in[8];
    float* out = (float*)d_out;

    // workspace layout (192 MB total).  region0 (first 64 MB) is used twice:
    //   phase 1: xb (32 MB bf16 x) + wt (6 MB bf16 W^T x3)  -- dead after qkv
    //   phase 2: st (64 MB fp32 transposed scores)
    char* ws = (char*)d_ws;
    unsigned short* xb = (unsigned short*)ws;                          // 32 MB
    unsigned short* wt = xb + (size_t)B_ * T_ * D_;                    // 6 MB
    float*          st = (float*)ws;                                   // 64 MB (aliases xb/wt)
    unsigned short* qb = (unsigned short*)(ws + ((size_t)64 << 20));   // 32 MB
    unsigned short* kb = qb + (size_t)B_ * T_ * D_;                    // 32 MB
    unsigned short* vb = kb + (size_t)B_ * T_ * D_;                    // 32 MB
    unsigned short* pt = vb + (size_t)B_ * T_ * D_;                    // 32 MB

    cvt_x      <<<dim3(16384),      256, 0, stream>>>(x, xb);
    cvt_wt     <<<dim3(16, 16, 3),  256, 0, stream>>>(Wq, Wk, Wv, wt);
    qkv_gemm2  <<<dim3(8, 128, 3),  256, 0, stream>>>(xb, wt, bq, bk, bv, qb, kb, vb);
    score_gemm <<<dim3(8, 8, 16),   256, 0, stream>>>(kb, qb, st);
    softmax_rows<<<dim3(B_ * T_),   256, 0, stream>>>(st, pt);
    init_out   <<<1, 64, 0, stream>>>(out, bfc);
    pv_fc      <<<dim3(8, 8, 16),   256, 0, stream>>>(pt, vb, Wfc, out);
}

// Round 3
// 424.202 us; speedup vs baseline: 1.4315x; 1.0637x over previous
//
#include <hip/hip_runtime.h>
#include <hip/hip_bf16.h>

// Problem constants
#define B_ 16
#define T_ 1024
#define D_ 1024

using frag8 = __attribute__((ext_vector_type(8))) short;   // 8 bf16 (4 VGPRs)
using f32x4 = __attribute__((ext_vector_type(4))) float;   // 4 fp32 acc

__device__ inline unsigned short f2bf(float f) {
    union { float f; unsigned u; } v; v.f = f;
    unsigned r = v.u + 0x7FFF + ((v.u >> 16) & 1);   // round-nearest-even
    return (unsigned short)(r >> 16);
}

// ---------------------------------------------------------------------------
// K0a: x fp32 -> bf16  (16M elems, float4 in / ushort4 out, pure BW)
// ---------------------------------------------------------------------------
__global__ __launch_bounds__(256)
void cvt_x(const float* __restrict__ x, unsigned short* __restrict__ xb) {
    int i = blockIdx.x * 256 + threadIdx.x;          // group of 4 elems
    float4 v = ((const float4*)x)[i];
    ushort4 o;
    o.x = f2bf(v.x); o.y = f2bf(v.y); o.z = f2bf(v.z); o.w = f2bf(v.w);
    ((ushort4*)xb)[i] = o;
}

// ---------------------------------------------------------------------------
// K0b: W fp32 [k][n] -> bf16 TRANSPOSED wt[z][n][k]  (64x64 LDS tile transpose)
// grid (16,16,3) block 256
// ---------------------------------------------------------------------------
__global__ __launch_bounds__(256)
void cvt_wt(const float* __restrict__ Wq, const float* __restrict__ Wk,
            const float* __restrict__ Wv, unsigned short* __restrict__ wt) {
    __shared__ unsigned short t[64][65];
    const float* W = (blockIdx.z == 0) ? Wq : (blockIdx.z == 1 ? Wk : Wv);
    const int n0 = blockIdx.x * 64, k0 = blockIdx.y * 64;
    const int tn = threadIdx.x & 63;   // coalesced over n
    const int tk = threadIdx.x >> 6;   // 0..3
#pragma unroll
    for (int it = 0; it < 16; ++it) {
        int k = tk + it * 4;
        t[tn][k] = f2bf(W[(size_t)(k0 + k) * D_ + n0 + tn]);
    }
    __syncthreads();
    const int wk = threadIdx.x & 63;   // coalesced over k
    const int wn = threadIdx.x >> 6;
#pragma unroll
    for (int it = 0; it < 16; ++it) {
        int n = wn + it * 4;
        wt[((size_t)blockIdx.z << 20) + (size_t)(n0 + n) * D_ + k0 + wk] = t[n][wk];
    }
}

// ---------------------------------------------------------------------------
// K0c: bf16 1024x1024 per-batch transpose.  out[b][c][r] = in[b][r][c]
// grid (16,16,B) block 256.  8B vector read/write, padded LDS.
// ---------------------------------------------------------------------------
__global__ __launch_bounds__(256)
void transpose_bf16(const unsigned short* __restrict__ in,
                    unsigned short* __restrict__ outp) {
    __shared__ unsigned short t[64][68];
    const size_t base = (size_t)blockIdx.z << 20;
    const int c0 = blockIdx.x * 64, r0 = blockIdx.y * 64;
    const int tc = (threadIdx.x & 15) * 4;
    const int tr = threadIdx.x >> 4;   // 0..15
#pragma unroll
    for (int p = 0; p < 4; ++p) {
        int r = tr + p * 16;
        *(ushort4*)&t[r][tc] =
            *(const ushort4*)&in[base + (size_t)(r0 + r) * 1024 + c0 + tc];
    }
    __syncthreads();
    const int wr = (threadIdx.x & 15) * 4;   // original row base
    const int wc = threadIdx.x >> 4;
#pragma unroll
    for (int p = 0; p < 4; ++p) {
        int c = wc + p * 16;
        ushort4 o;
        o.x = t[wr + 0][c]; o.y = t[wr + 1][c];
        o.z = t[wr + 2][c]; o.w = t[wr + 3][c];
        *(ushort4*)&outp[base + (size_t)(c0 + c) * 1024 + r0 + wr] = o;
    }
}

// ---------------------------------------------------------------------------
// K1: fused Q/K/V projection, m97-style (unchanged from R2).
// grid: (8, 128, 3) linear = x + 8*y + 1024*z.   block: 256
// ---------------------------------------------------------------------------
__global__ __launch_bounds__(256)
void qkv_gemm2(const unsigned short* __restrict__ xb,
               const unsigned short* __restrict__ wt,
               const float* __restrict__ bq, const float* __restrict__ bk,
               const float* __restrict__ bv,
               unsigned short* __restrict__ qb,
               unsigned short* __restrict__ kb,
               unsigned short* __restrict__ vb) {
    __shared__ __align__(16) unsigned short As[128 * 32];
    __shared__ __align__(16) unsigned short Bs[128 * 32];

    const int l   = blockIdx.x + 8 * blockIdx.y + 1024 * blockIdx.z;
    const int xcd = l & 7;
    const int idx = l >> 3;                 // 0..383
    const int slab = xcd * 3 + (idx >> 7);  // 0..23
    const int mblk = idx & 127;
    const int z    = slab >> 3;
    const int nblk = slab & 7;

    const int m0 = mblk * 128, n0 = nblk * 128;
    const unsigned short* Wz = wt + ((size_t)z << 20);
    const float* bias  = (z == 0) ? bq : (z == 1 ? bk : bv);
    unsigned short* out = (z == 0) ? qb : (z == 1 ? kb : vb);

    const int tid = threadIdx.x, lane = tid & 63, wave = tid >> 6;
    const int wm = (wave >> 1) * 64, wn = (wave & 1) * 64;

    f32x4 acc[4][4];
#pragma unroll
    for (int i = 0; i < 4; i++)
#pragma unroll
        for (int j = 0; j < 4; j++) acc[i][j] = (f32x4){0.f, 0.f, 0.f, 0.f};

    const int srow = lane >> 2;          // row within 16-row group
    const int sk   = (lane & 3) * 8;     // k elem offset
    const int fr = lane & 15, fk = (lane >> 4) * 8;

    for (int k0 = 0; k0 < D_; k0 += 32) {
#pragma unroll
        for (int it = 0; it < 2; ++it) {
            const int rb = wave * 2 + it;           // 16-row group 0..7
            const int r  = rb * 16 + srow;
            __builtin_amdgcn_global_load_lds(
                (const __attribute__((address_space(1))) unsigned int*)
                    (xb + (size_t)(m0 + r) * D_ + k0 + sk),
                (__attribute__((address_space(3))) unsigned int*)(As + rb * 512),
                16, 0, 0);
            __builtin_amdgcn_global_load_lds(
                (const __attribute__((address_space(1))) unsigned int*)
                    (Wz + (size_t)(n0 + r) * D_ + k0 + sk),
                (__attribute__((address_space(3))) unsigned int*)(Bs + rb * 512),
                16, 0, 0);
        }
        __syncthreads();

        frag8 af[4], bff[4];
#pragma unroll
        for (int t = 0; t < 4; ++t)
            af[t] = *(const frag8*)&As[(wm + t * 16 + fr) * 32 + fk];
#pragma unroll
        for (int t = 0; t < 4; ++t)
            bff[t] = *(const frag8*)&Bs[(wn + t * 16 + fr) * 32 + fk];
#pragma unroll
        for (int i = 0; i < 4; i++)
#pragma unroll
            for (int j = 0; j < 4; j++)
                acc[i][j] = __builtin_amdgcn_mfma_f32_16x16x32_bf16(
                    af[i], bff[j], acc[i][j], 0, 0, 0);
        __syncthreads();
    }

    const int col   = lane & 15;
    const int rbase = (lane >> 4) * 4;
#pragma unroll
    for (int i = 0; i < 4; i++) {
#pragma unroll
        for (int j = 0; j < 4; j++) {
            int gn = n0 + wn + j * 16 + col;
            float bb = bias[gn];
#pragma unroll
            for (int r = 0; r < 4; r++) {
                int gm = m0 + wm + i * 16 + rbase + r;
                out[(size_t)gm * D_ + gn] = f2bf(acc[i][j][r] + bb);
            }
        }
    }
}

// ---------------------------------------------------------------------------
// K2: scores TRANSPOSED, m97-style.  ST[b][i=key][j=query] = scale*(k_i.q_j)
// Both operands k-major bf16.  grid: (8, 8, 16)
// ---------------------------------------------------------------------------
__global__ __launch_bounds__(256)
void score_gemm2(const unsigned short* __restrict__ kbuf,
                 const unsigned short* __restrict__ qbuf,
                 float* __restrict__ st) {
    __shared__ __align__(16) unsigned short As[128 * 32];
    __shared__ __align__(16) unsigned short Bs[128 * 32];

    const int b  = blockIdx.z;
    const int j0 = blockIdx.x * 128;   // query block
    const int i0 = blockIdx.y * 128;   // key block
    const unsigned short* A  = kbuf + (size_t)b * T_ * D_;
    const unsigned short* Bq = qbuf + (size_t)b * T_ * D_;

    const int tid = threadIdx.x, lane = tid & 63, wave = tid >> 6;
    const int wm = (wave >> 1) * 64, wn = (wave & 1) * 64;

    f32x4 acc[4][4];
#pragma unroll
    for (int i = 0; i < 4; i++)
#pragma unroll
        for (int j = 0; j < 4; j++) acc[i][j] = (f32x4){0.f, 0.f, 0.f, 0.f};

    const int srow = lane >> 2;
    const int sk   = (lane & 3) * 8;
    const int fr = lane & 15, fk = (lane >> 4) * 8;

    for (int k0 = 0; k0 < D_; k0 += 32) {
#pragma unroll
        for (int it = 0; it < 2; ++it) {
            const int rb = wave * 2 + it;
            const int r  = rb * 16 + srow;
            __builtin_amdgcn_global_load_lds(
                (const __attribute__((address_space(1))) unsigned int*)
                    (A + (size_t)(i0 + r) * D_ + k0 + sk),
                (__attribute__((address_space(3))) unsigned int*)(As + rb * 512),
                16, 0, 0);
            __builtin_amdgcn_global_load_lds(
                (const __attribute__((address_space(1))) unsigned int*)
                    (Bq + (size_t)(j0 + r) * D_ + k0 + sk),
                (__attribute__((address_space(3))) unsigned int*)(Bs + rb * 512),
                16, 0, 0);
        }
        __syncthreads();

        frag8 af[4], bff[4];
#pragma unroll
        for (int t = 0; t < 4; ++t)
            af[t] = *(const frag8*)&As[(wm + t * 16 + fr) * 32 + fk];
#pragma unroll
        for (int t = 0; t < 4; ++t)
            bff[t] = *(const frag8*)&Bs[(wn + t * 16 + fr) * 32 + fk];
#pragma unroll
        for (int i = 0; i < 4; i++)
#pragma unroll
            for (int j = 0; j < 4; j++)
                acc[i][j] = __builtin_amdgcn_mfma_f32_16x16x32_bf16(
                    af[i], bff[j], acc[i][j], 0, 0, 0);
        __syncthreads();
    }

    const float scale = 0.03125f;  // 1/sqrt(1024)
    const int col   = lane & 15;
    const int rbase = (lane >> 4) * 4;
    float* outb = st + (size_t)b * T_ * T_;
#pragma unroll
    for (int i = 0; i < 4; i++) {
#pragma unroll
        for (int j = 0; j < 4; j++) {
            int gj = j0 + wn + j * 16 + col;
#pragma unroll
            for (int r = 0; r < 4; r++) {
                int gi = i0 + wm + i * 16 + rbase + r;
                outb[(size_t)gi * T_ + gj] = acc[i][j][r] * scale;
            }
        }
    }
}

// ---------------------------------------------------------------------------
// K3: row softmax over ST rows (= softmax over the QUERY axis of attn),
// write bf16 P^T.  grid: B*T = 16384 blocks, 256 threads.
// ---------------------------------------------------------------------------
__global__ __launch_bounds__(256)
void softmax_rows(const float* __restrict__ st, unsigned short* __restrict__ pt) {
    const size_t row = blockIdx.x;
    const float* r = st + row * T_;
    unsigned short* o = pt + row * T_;
    const int tid  = threadIdx.x;
    const int lane = tid & 63;
    const int wave = tid >> 6;

    float v0 = r[tid], v1 = r[tid + 256], v2 = r[tid + 512], v3 = r[tid + 768];
    float mx = fmaxf(fmaxf(v0, v1), fmaxf(v2, v3));
#pragma unroll
    for (int off = 32; off; off >>= 1) mx = fmaxf(mx, __shfl_down(mx, off));
    __shared__ float sm[4];
    if (lane == 0) sm[wave] = mx;
    __syncthreads();
    mx = fmaxf(fmaxf(sm[0], sm[1]), fmaxf(sm[2], sm[3]));

    float e0 = __expf(v0 - mx), e1 = __expf(v1 - mx);
    float e2 = __expf(v2 - mx), e3 = __expf(v3 - mx);
    float s = e0 + e1 + e2 + e3;
#pragma unroll
    for (int off = 32; off; off >>= 1) s += __shfl_down(s, off);
    __shared__ float ss[4];
    if (lane == 0) ss[wave] = s;
    __syncthreads();
    s = ss[0] + ss[1] + ss[2] + ss[3];
    float inv = 1.f / s;

    o[tid]       = f2bf(e0 * inv);
    o[tid + 256] = f2bf(e1 * inv);
    o[tid + 512] = f2bf(e2 * inv);
    o[tid + 768] = f2bf(e3 * inv);
}

// ---------------------------------------------------------------------------
// K4: O[q][d] = sum_i pq[q][i] * vt[d][i]  (both k-major after transposes),
// fused rank-1 FC:  out[b] += sum_{q,d} O[q][d]*Wfc[q*D+d].  grid (8,8,16)
// ---------------------------------------------------------------------------
__global__ __launch_bounds__(256)
void pv_fc2(const unsigned short* __restrict__ pq,
            const unsigned short* __restrict__ vt,
            const float* __restrict__ Wfc,
            float* __restrict__ outv) {
    __shared__ __align__(16) unsigned short As[128 * 32];
    __shared__ __align__(16) unsigned short Bs[128 * 32];

    const int b  = blockIdx.z;
    const int d0 = blockIdx.x * 128;
    const int q0 = blockIdx.y * 128;
    const unsigned short* P = pq + (size_t)b * T_ * T_;  // [q][i]
    const unsigned short* V = vt + (size_t)b * T_ * D_;  // [d][i]

    const int tid = threadIdx.x, lane = tid & 63, wave = tid >> 6;
    const int wm = (wave >> 1) * 64, wn = (wave & 1) * 64;

    f32x4 acc[4][4];
#pragma unroll
    for (int i = 0; i < 4; i++)
#pragma unroll
        for (int j = 0; j < 4; j++) acc[i][j] = (f32x4){0.f, 0.f, 0.f, 0.f};

    const int srow = lane >> 2;
    const int sk   = (lane & 3) * 8;
    const int fr = lane & 15, fk = (lane >> 4) * 8;

    for (int k0 = 0; k0 < T_; k0 += 32) {
#pragma unroll
        for (int it = 0; it < 2; ++it) {
            const int rb = wave * 2 + it;
            const int r  = rb * 16 + srow;
            __builtin_amdgcn_global_load_lds(
                (const __attribute__((address_space(1))) unsigned int*)
                    (P + (size_t)(q0 + r) * T_ + k0 + sk),
                (__attribute__((address_space(3))) unsigned int*)(As + rb * 512),
                16, 0, 0);
            __builtin_amdgcn_global_load_lds(
                (const __attribute__((address_space(1))) unsigned int*)
                    (V + (size_t)(d0 + r) * T_ + k0 + sk),
                (__attribute__((address_space(3))) unsigned int*)(Bs + rb * 512),
                16, 0, 0);
        }
        __syncthreads();

        frag8 af[4], bff[4];
#pragma unroll
        for (int t = 0; t < 4; ++t)
            af[t] = *(const frag8*)&As[(wm + t * 16 + fr) * 32 + fk];
#pragma unroll
        for (int t = 0; t < 4; ++t)
            bff[t] = *(const frag8*)&Bs[(wn + t * 16 + fr) * 32 + fk];
#pragma unroll
        for (int i = 0; i < 4; i++)
#pragma unroll
            for (int j = 0; j < 4; j++)
                acc[i][j] = __builtin_amdgcn_mfma_f32_16x16x32_bf16(
                    af[i], bff[j], acc[i][j], 0, 0, 0);
        __syncthreads();
    }

    // fused FC epilogue: local dot with Wfc, then block-reduce + atomicAdd
    const int col   = lane & 15;
    const int rbase = (lane >> 4) * 4;
    float local = 0.f;
#pragma unroll
    for (int i = 0; i < 4; i++) {
#pragma unroll
        for (int j = 0; j < 4; j++) {
            int gd = d0 + wn + j * 16 + col;
#pragma unroll
            for (int r = 0; r < 4; r++) {
                int gq = q0 + wm + i * 16 + rbase + r;
                local += acc[i][j][r] * Wfc[(size_t)gq * D_ + gd];
            }
        }
    }
#pragma unroll
    for (int off = 32; off; off >>= 1) local += __shfl_down(local, off);
    __shared__ float wsum[4];
    if (lane == 0) wsum[wave] = local;
    __syncthreads();
    if (tid == 0) {
        float t = wsum[0] + wsum[1] + wsum[2] + wsum[3];
        atomicAdd(&outv[b], t);
    }
}

// K5: init output with bias (d_out is re-poisoned before every timed launch)
__global__ void init_out(float* __restrict__ out, const float* __restrict__ bfc) {
    if (threadIdx.x < B_) out[threadIdx.x] = bfc[0];
}

extern "C" void kernel_launch(void* const* d_in, const int* in_sizes, int n_in,
                              void* d_out, int out_size, void* d_ws, size_t ws_size,
                              hipStream_t stream) {
    const float* x   = (const float*)d_in[0];
    const float* Wq  = (const float*)d_in[1];
    const float* bq  = (const float*)d_in[2];
    const float* Wk  = (const float*)d_in[3];
    const float* bk  = (const float*)d_in[4];
    const float* Wv  = (const float*)d_in[5];
    const float* bv  = (const float*)d_in[6];
    const float* Wfc = (const float*)d_in[7];
    const float* bfc = (const float*)d_in[8];
    float* out = (float*)d_out;

    // workspace layout (192 MB, aliased by liveness):
    //  S0 [0,64):   phase1 xb(32)+wt(6)  -> phase2 st(64 fp32)
    //  S1 [64,96):  qb  (dead after score)  -> pq
    //  S2 [96,128): kb  (dead after score)  -> vt
    //  S3 [128,160): vb (dead after v-transpose)
    //  S4 [160,192): pt (dead after p-transpose)
    char* ws = (char*)d_ws;
    unsigned short* xb = (unsigned short*)ws;                          // 32 MB
    unsigned short* wt = xb + (size_t)B_ * T_ * D_;                    // 6 MB
    float*          st = (float*)ws;                                   // 64 MB (aliases xb/wt)
    unsigned short* qb = (unsigned short*)(ws + ((size_t)64  << 20));  // 32 MB
    unsigned short* kb = (unsigned short*)(ws + ((size_t)96  << 20));  // 32 MB
    unsigned short* vb = (unsigned short*)(ws + ((size_t)128 << 20));  // 32 MB
    unsigned short* pt = (unsigned short*)(ws + ((size_t)160 << 20));  // 32 MB
    unsigned short* pq = qb;   // aliases qb after score_gemm2
    unsigned short* vt = kb;   // aliases kb after score_gemm2

    cvt_x        <<<dim3(16384),      256, 0, stream>>>(x, xb);
    cvt_wt       <<<dim3(16, 16, 3),  256, 0, stream>>>(Wq, Wk, Wv, wt);
    qkv_gemm2    <<<dim3(8, 128, 3),  256, 0, stream>>>(xb, wt, bq, bk, bv, qb, kb, vb);
    score_gemm2  <<<dim3(8, 8, 16),   256, 0, stream>>>(kb, qb, st);
    softmax_rows <<<dim3(B_ * T_),    256, 0, stream>>>(st, pt);
    transpose_bf16<<<dim3(16, 16, 16), 256, 0, stream>>>(pt, pq);
    transpose_bf16<<<dim3(16, 16, 16), 256, 0, stream>>>(vb, vt);
    init_out     <<<1, 64, 0, stream>>>(out, bfc);
    pv_fc2       <<<dim3(8, 8, 16),   256, 0, stream>>>(pq, vt, Wfc, out);
}